// Round 1
// baseline (14.581 us; speedup 1.0000x reference)
//
#include <hip/hip_runtime.h>

#define DIM 496  // C(32,2)

// Index of sorted pair (r,s), r<s, in itertools.combinations(range(32),2) order.
__device__ __forceinline__ int pair_idx(int r, int s) {
    return (r * (63 - r)) / 2 + (s - r - 1);
}

// Decode combination index -> (p,q), p<q.
__device__ __forceinline__ void decode_pair(int i, int& p, int& q) {
    p = (int)((63.0f - sqrtf(3969.0f - 8.0f * (float)i)) * 0.5f);
    while ((p + 1) * (62 - p) / 2 <= i) ++p;  // offset(p+1) <= i -> p too small
    while (p * (63 - p) / 2 > i) --p;         // offset(p)   >  i -> p too big
    q = i - p * (63 - p) / 2 + p + 1;
}

__global__ __launch_bounds__(256)
void rbs_density_kernel(const float* __restrict__ rho,
                        const float* __restrict__ ang,
                        float* __restrict__ out)
{
    __shared__ float sc[16];
    __shared__ float ss[16];
    __shared__ float v[DIM];

    const int tid = threadIdx.x;
    if (tid < 16) {
        // gate 15 (qubits 30,31) is identity: c=1, s=0
        float t = (tid < 15) ? ang[tid] : 0.0f;
        sc[tid] = cosf(t);
        ss[tid] = (tid < 15) ? sinf(t) : 0.0f;
    }
    __syncthreads();

    const int i = blockIdx.x;  // output row (weight-2 basis index)
    const int b = blockIdx.y;  // batch

    int p, q;
    decode_pair(i, p, q);

    const float* base = rho + (size_t)b * DIM * DIM;

    // Row pass: v[m] = sum_l U[i,l] * rho[b,l,m]   (<=4 rows, coalesced)
    if ((p >> 1) == (q >> 1)) {
        // both qubits in the same gate pair -> identity row
        const float* r0 = base + (size_t)i * DIM;
        for (int m = tid; m < DIM; m += 256) v[m] = r0[m];
    } else {
        const float upp = sc[p >> 1];
        const float upP = (p & 1) ? -ss[p >> 1] : ss[p >> 1];  // u[p, p^1]
        const float uqq = sc[q >> 1];
        const float uqQ = (q & 1) ? -ss[q >> 1] : ss[q >> 1];  // u[q, q^1]
        const int l1 = pair_idx(p ^ 1, q);
        const int l2 = pair_idx(p, q ^ 1);
        const int l3 = pair_idx(p ^ 1, q ^ 1);
        const float a0 = upp * uqq, a1 = upP * uqq;
        const float a2 = upp * uqQ, a3 = upP * uqQ;
        const float* r0 = base + (size_t)i  * DIM;
        const float* r1 = base + (size_t)l1 * DIM;
        const float* r2 = base + (size_t)l2 * DIM;
        const float* r3 = base + (size_t)l3 * DIM;
        for (int m = tid; m < DIM; m += 256)
            v[m] = a0 * r0[m] + a1 * r1[m] + a2 * r2[m] + a3 * r3[m];
    }
    __syncthreads();

    // Column pass: out[b,i,j] = sum_m U[j,m] * v[m]   (<=4 LDS reads per j)
    float* orow = out + (size_t)b * DIM * DIM + (size_t)i * DIM;
    for (int j = tid; j < DIM; j += 256) {
        int pj, qj;
        decode_pair(j, pj, qj);
        float res;
        if ((pj >> 1) == (qj >> 1)) {
            res = v[j];
        } else {
            const float wpp = sc[pj >> 1];
            const float wpP = (pj & 1) ? -ss[pj >> 1] : ss[pj >> 1];
            const float wqq = sc[qj >> 1];
            const float wqQ = (qj & 1) ? -ss[qj >> 1] : ss[qj >> 1];
            const int m1 = pair_idx(pj ^ 1, qj);
            const int m2 = pair_idx(pj, qj ^ 1);
            const int m3 = pair_idx(pj ^ 1, qj ^ 1);
            res = (wpp * wqq) * v[j]  + (wpP * wqq) * v[m1]
                + (wpp * wqQ) * v[m2] + (wpP * wqQ) * v[m3];
        }
        orow[j] = res;
    }
}

extern "C" void kernel_launch(void* const* d_in, const int* in_sizes, int n_in,
                              void* d_out, int out_size, void* d_ws, size_t ws_size,
                              hipStream_t stream) {
    const float* rho = (const float*)d_in[0];
    const float* ang = (const float*)d_in[1];
    float* out = (float*)d_out;
    dim3 grid(DIM, 8, 1);
    rbs_density_kernel<<<grid, dim3(256, 1, 1), 0, stream>>>(rho, ang, out);
}

// Round 2
// 10.272 us; speedup vs baseline: 1.4195x; 1.4195x over previous
//
#include <hip/hip_runtime.h>

#define DIM 496  // C(32,2)

// Index of sorted pair (r,s), r<s, in itertools.combinations(range(32),2) order.
__device__ __forceinline__ int pair_idx(int r, int s) {
    return (r * (63 - r)) / 2 + (s - r - 1);
}

// Decode combination index -> (p,q), p<q, over 32 modes.
__device__ __forceinline__ void decode_pair(int i, int& p, int& q) {
    p = (int)((63.0f - sqrtf(3969.0f - 8.0f * (float)i)) * 0.5f);
    while ((p + 1) * (62 - p) / 2 <= i) ++p;
    while (p * (63 - p) / 2 > i) --p;
    q = i - p * (63 - p) / 2 + p + 1;
}

// Decode combination index -> (gp,gq), gp<gq, over 16 gates. offset(g)=g*(31-g)/2
__device__ __forceinline__ void decode_gate_pair(int o, int& gp, int& gq) {
    gp = 0;
    while ((gp + 1) * (30 - gp) / 2 <= o) ++gp;
    gq = o - gp * (31 - gp) / 2 + gp + 1;
}

__global__ __launch_bounds__(256)
void rbs_orbit_kernel(const float* __restrict__ rho,
                      const float* __restrict__ ang,
                      float* __restrict__ out)
{
    __shared__ float sc[16], ss[16];
    __shared__ float v[4][DIM];   // row-pass results for the 4 output rows

    const int tid = threadIdx.x;
    const int blk = blockIdx.x;   // 0..119 orbits, 120..123 identity groups
    const int b   = blockIdx.y;

    if (tid < 16) {
        float t = (tid < 15) ? ang[tid] : 0.0f;
        sc[tid] = cosf(t);
        ss[tid] = (tid < 15) ? sinf(t) : 0.0f;
    }
    __syncthreads();

    // Per-block (uniform) row set + 4x4 row-combination matrix.
    int rows[4];
    float M[4][4];
    if (blk < 120) {
        int gp, gq;
        decode_gate_pair(blk, gp, gq);
        const int p0 = 2 * gp, q0 = 2 * gq;
        rows[0] = pair_idx(p0,     q0);
        rows[1] = pair_idx(p0,     q0 + 1);
        rows[2] = pair_idx(p0 + 1, q0);
        rows[3] = pair_idx(p0 + 1, q0 + 1);
        const float cp = sc[gp], sp = ss[gp];
        const float cq = sc[gq], sq = ss[gq];
        // u[2g+a, 2g+c]: [[c, s], [-s, c]]
        const float up[2][2] = {{cp, sp}, {-sp, cp}};
        const float uq[2][2] = {{cq, sq}, {-sq, cq}};
        #pragma unroll
        for (int a = 0; a < 2; ++a)
            #pragma unroll
            for (int bb = 0; bb < 2; ++bb)
                #pragma unroll
                for (int c = 0; c < 2; ++c)
                    #pragma unroll
                    for (int d = 0; d < 2; ++d)
                        M[a * 2 + bb][c * 2 + d] = up[a][c] * uq[bb][d];
    } else {
        const int k = blk - 120;
        #pragma unroll
        for (int t = 0; t < 4; ++t) {
            const int g = 4 * k + t;
            rows[t] = pair_idx(2 * g, 2 * g + 1);
        }
        #pragma unroll
        for (int a = 0; a < 4; ++a)
            #pragma unroll
            for (int c = 0; c < 4; ++c)
                M[a][c] = (a == c) ? 1.0f : 0.0f;
    }

    const float* base = rho + (size_t)b * DIM * DIM;

    // Row pass (float4): v[r][:] = sum_c M[r][c] * rho[rows[c]][:]
    // 496 floats = 124 float4 per row; rows are 16B-aligned (496*4 % 16 == 0).
    if (tid < 124) {
        const float4 x0 = reinterpret_cast<const float4*>(base + (size_t)rows[0] * DIM)[tid];
        const float4 x1 = reinterpret_cast<const float4*>(base + (size_t)rows[1] * DIM)[tid];
        const float4 x2 = reinterpret_cast<const float4*>(base + (size_t)rows[2] * DIM)[tid];
        const float4 x3 = reinterpret_cast<const float4*>(base + (size_t)rows[3] * DIM)[tid];
        #pragma unroll
        for (int r = 0; r < 4; ++r) {
            float4 y;
            y.x = M[r][0] * x0.x + M[r][1] * x1.x + M[r][2] * x2.x + M[r][3] * x3.x;
            y.y = M[r][0] * x0.y + M[r][1] * x1.y + M[r][2] * x2.y + M[r][3] * x3.y;
            y.z = M[r][0] * x0.z + M[r][1] * x1.z + M[r][2] * x2.z + M[r][3] * x3.z;
            y.w = M[r][0] * x0.w + M[r][1] * x1.w + M[r][2] * x2.w + M[r][3] * x3.w;
            reinterpret_cast<float4*>(&v[r][0])[tid] = y;
        }
    }
    __syncthreads();

    // Column pass: out[rows[r]][j] = sum_m U[j,m] * v[r][m]  (<=4 LDS reads,
    // j-coefficients computed once, reused for all 4 output rows).
    float* obase = out + (size_t)b * DIM * DIM;
    for (int j = tid; j < DIM; j += 256) {
        int pj, qj;
        decode_pair(j, pj, qj);
        float r0, r1, r2, r3;
        if ((pj >> 1) == (qj >> 1)) {
            r0 = v[0][j]; r1 = v[1][j]; r2 = v[2][j]; r3 = v[3][j];
        } else {
            const float wpp = sc[pj >> 1];
            const float wpP = (pj & 1) ? -ss[pj >> 1] : ss[pj >> 1];
            const float wqq = sc[qj >> 1];
            const float wqQ = (qj & 1) ? -ss[qj >> 1] : ss[qj >> 1];
            const int m1 = pair_idx(pj ^ 1, qj);
            const int m2 = pair_idx(pj, qj ^ 1);
            const int m3 = pair_idx(pj ^ 1, qj ^ 1);
            const float c0 = wpp * wqq, c1 = wpP * wqq;
            const float c2 = wpp * wqQ, c3 = wpP * wqQ;
            r0 = c0 * v[0][j] + c1 * v[0][m1] + c2 * v[0][m2] + c3 * v[0][m3];
            r1 = c0 * v[1][j] + c1 * v[1][m1] + c2 * v[1][m2] + c3 * v[1][m3];
            r2 = c0 * v[2][j] + c1 * v[2][m1] + c2 * v[2][m2] + c3 * v[2][m3];
            r3 = c0 * v[3][j] + c1 * v[3][m1] + c2 * v[3][m2] + c3 * v[3][m3];
        }
        obase[(size_t)rows[0] * DIM + j] = r0;
        obase[(size_t)rows[1] * DIM + j] = r1;
        obase[(size_t)rows[2] * DIM + j] = r2;
        obase[(size_t)rows[3] * DIM + j] = r3;
    }
}

extern "C" void kernel_launch(void* const* d_in, const int* in_sizes, int n_in,
                              void* d_out, int out_size, void* d_ws, size_t ws_size,
                              hipStream_t stream) {
    const float* rho = (const float*)d_in[0];
    const float* ang = (const float*)d_in[1];
    float* out = (float*)d_out;
    dim3 grid(124, 8, 1);
    rbs_orbit_kernel<<<grid, dim3(256, 1, 1), 0, stream>>>(rho, ang, out);
}

// Round 3
// 10.209 us; speedup vs baseline: 1.4283x; 1.0062x over previous
//
#include <hip/hip_runtime.h>

#define DIM 496  // C(32,2)

__device__ __forceinline__ int pair_off(int p) { return (p * (63 - p)) >> 1; }
__device__ __forceinline__ int pair_idx(int r, int s) { return pair_off(r) + (s - r - 1); }

__global__ __launch_bounds__(256)
void rbs_orbit_kernel(const float* __restrict__ rho,
                      const float* __restrict__ ang,
                      float* __restrict__ out)
{
    __shared__ float sc[16], ss[16];
    __shared__ unsigned char pp[DIM];   // j -> smaller mode p
    __shared__ float v[4][DIM];         // row-pass results

    const int tid = threadIdx.x;
    const int blk = blockIdx.x;   // 0..119 gate-pair orbits, 120..123 identity groups
    const int b   = blockIdx.y;

    // ---- orbit decode (uniform scalar work) ----
    int rows[4];
    int gp = 16, gq = 16;
    if (blk < 120) {
        gp = 0;
        while ((gp + 1) * (30 - gp) / 2 <= blk) ++gp;
        gq = blk - gp * (31 - gp) / 2 + gp + 1;
        const int p0 = 2 * gp, q0 = 2 * gq;
        rows[0] = pair_idx(p0,     q0);
        rows[1] = pair_idx(p0,     q0 + 1);
        rows[2] = pair_idx(p0 + 1, q0);
        rows[3] = pair_idx(p0 + 1, q0 + 1);
    } else {
        const int k = blk - 120;
        #pragma unroll
        for (int t = 0; t < 4; ++t) {
            const int g = 4 * k + t;
            rows[t] = pair_idx(2 * g, 2 * g + 1);
        }
    }

    // ---- issue global loads FIRST (float2 x 248 lanes: all 4 waves busy) ----
    const float* base = rho + (size_t)b * DIM * DIM;
    const bool ld = (tid < 248);
    float2 x0, x1, x2, x3;
    if (ld) {
        x0 = reinterpret_cast<const float2*>(base + (size_t)rows[0] * DIM)[tid];
        x1 = reinterpret_cast<const float2*>(base + (size_t)rows[1] * DIM)[tid];
        x2 = reinterpret_cast<const float2*>(base + (size_t)rows[2] * DIM)[tid];
        x3 = reinterpret_cast<const float2*>(base + (size_t)rows[3] * DIM)[tid];
    }

    // ---- LDS tables, overlapped with load latency ----
    if (tid < 16) {
        const float t = (tid < 15) ? ang[tid] : 0.0f;
        float s, c;
        __sincosf(t, &s, &c);
        sc[tid] = c;
        ss[tid] = (tid < 15) ? s : 0.0f;
    }
    if (tid >= 64 && tid < 126) {  // 2 lanes per p fill the p-lookup
        const int l = tid - 64;
        const int p = l >> 1;
        const int off = pair_off(p);
        for (int q = p + 1 + (l & 1); q < 32; q += 2)
            pp[off + q - p - 1] = (unsigned char)p;
    }

    // ---- per-thread M (uniform, no LDS dependency -> no extra barrier) ----
    float M[4][4];
    if (blk < 120) {
        const float tp = ang[gp];
        const float tq = (gq < 15) ? ang[gq] : 0.0f;
        float sp_, cp, sq_, cq;
        __sincosf(tp, &sp_, &cp);
        __sincosf(tq, &sq_, &cq);
        const float up[2][2] = {{cp, sp_}, {-sp_, cp}};
        const float uq[2][2] = {{cq, sq_}, {-sq_, cq}};
        #pragma unroll
        for (int a = 0; a < 2; ++a)
            #pragma unroll
            for (int bb = 0; bb < 2; ++bb)
                #pragma unroll
                for (int c = 0; c < 2; ++c)
                    #pragma unroll
                    for (int d = 0; d < 2; ++d)
                        M[a * 2 + bb][c * 2 + d] = up[a][c] * uq[bb][d];
    } else {
        #pragma unroll
        for (int a = 0; a < 4; ++a)
            #pragma unroll
            for (int c = 0; c < 4; ++c)
                M[a][c] = (a == c) ? 1.0f : 0.0f;
    }

    // ---- combine loaded rows -> v (float2 writes) ----
    if (ld) {
        #pragma unroll
        for (int r = 0; r < 4; ++r) {
            float2 y;
            y.x = M[r][0] * x0.x + M[r][1] * x1.x + M[r][2] * x2.x + M[r][3] * x3.x;
            y.y = M[r][0] * x0.y + M[r][1] * x1.y + M[r][2] * x2.y + M[r][3] * x3.y;
            reinterpret_cast<float2*>(&v[r][0])[tid] = y;
        }
    }
    __syncthreads();

    // ---- column pass: table-driven decode, branchless, scalar coalesced stores ----
    float* obase = out + (size_t)b * DIM * DIM;
    #pragma unroll
    for (int it = 0; it < 2; ++it) {
        const int j = tid + it * 256;
        if (j < DIM) {
            const int p = pp[j];
            const int q = j - pair_off(p) + p + 1;
            const int g1 = p >> 1, g2 = q >> 1;
            const bool id = (g1 == g2);
            const int p1 = p ^ 1, q1 = q ^ 1;
            const int m1 = id ? j : pair_idx(p1, q);   // p1<q guaranteed when !id
            const int m2 = id ? j : pair_idx(p, q1);   // p<q1 guaranteed when !id
            const int m3 = id ? j : pair_idx(p1, q1);  // p1<q1 guaranteed when !id

            const float cp = sc[g1], sp_ = ss[g1];
            const float cq = sc[g2], sq_ = ss[g2];
            const float upp = cp;
            const float upP = (p & 1) ? -sp_ : sp_;
            const float uqq = cq;
            const float uqQ = (q & 1) ? -sq_ : sq_;
            const float c0 = id ? 1.0f : upp * uqq;
            const float c1 = id ? 0.0f : upP * uqq;
            const float c2 = id ? 0.0f : upp * uqQ;
            const float c3 = id ? 0.0f : upP * uqQ;

            #pragma unroll
            for (int r = 0; r < 4; ++r) {
                const float res = c0 * v[r][j] + c1 * v[r][m1]
                                + c2 * v[r][m2] + c3 * v[r][m3];
                obase[(size_t)rows[r] * DIM + j] = res;
            }
        }
    }
}

extern "C" void kernel_launch(void* const* d_in, const int* in_sizes, int n_in,
                              void* d_out, int out_size, void* d_ws, size_t ws_size,
                              hipStream_t stream) {
    const float* rho = (const float*)d_in[0];
    const float* ang = (const float*)d_in[1];
    float* out = (float*)d_out;
    dim3 grid(124, 8, 1);
    rbs_orbit_kernel<<<grid, dim3(256, 1, 1), 0, stream>>>(rho, ang, out);
}